// Round 9
// baseline (394.308 us; speedup 1.0000x reference)
//
#include <hip/hip_runtime.h>

#define NQ 8
#define DIM 256
#define NLAYER 256

typedef float v2f __attribute__((ext_vector_type(2)));

// ---------------- Kernel 1: dense per-(m,layer,qubit) gate construction ----
// U = Rz @ Ry @ Rx = [[alpha, beta], [-conj(beta), conj(alpha)]]
// g[((m*256 + i)*8 + q)] = {alpha_r, alpha_i, beta_r, beta_i}
__global__ __launch_bounds__(256) void gates_gen(
    const float* __restrict__ x,   // [M, 256]
    const float* __restrict__ p,   // [256, 8, 3]
    float4* __restrict__ g,
    int total)
{
    const int idx = blockIdx.x * 256 + threadIdx.x;
    if (idx >= total) return;
    const int q = idx & 7;
    const int i = (idx >> 3) & 255;
    const int m = idx >> 11;

    const float he = 0.5f * x[(m << 8) | i];
    const float* __restrict__ pl = p + (i * 8 + q) * 3;
    const float hx = he * pl[0];
    const float hy = he * pl[1];
    const float hz = he * pl[2];
    const float cx = __cosf(hx), sx = __sinf(hx);
    const float cy = __cosf(hy), sy = __sinf(hy);
    const float cz = __cosf(hz), sz = __sinf(hz);
    const float A = cy * cx, B = sy * sx, C = sy * cx, D = cy * sx;
    const float alr = cz * A + sz * B;
    const float ali = cz * B - sz * A;
    const float ber = -(cz * C + sz * D);
    const float bei = sz * C - cz * D;
    g[idx] = make_float4(alr, ali, ber, bei);
}

// Uniform broadcast from lane `srclane` (VALU->SGPR, no DS, no lgkmcnt).
__device__ __forceinline__ float bcast(float v, int srclane) {
    return __builtin_bit_cast(float,
        __builtin_amdgcn_readlane(__builtin_bit_cast(int, v), srclane));
}

// Lane-xor via DPP (pure VALU, zero-wait). CTRL: quad_perm or row_ror.
template <int CTRL>
__device__ __forceinline__ float dppf(float v) {
    return __builtin_bit_cast(float,
        __builtin_amdgcn_update_dpp(0, __builtin_bit_cast(int, v),
                                    CTRL, 0xf, 0xf, true));
}

// xor-exchange across lanes: DPP for masks 8/2/1, ds-shuffle otherwise.
template <int MASK>
__device__ __forceinline__ float lanexor(float v) {
    if constexpr (MASK == 8)      return dppf<0x128>(v);  // row_ror:8
    else if constexpr (MASK == 2) return dppf<0x4E>(v);   // quad_perm [2,3,0,1]
    else if constexpr (MASK == 1) return dppf<0xB1>(v);   // quad_perm [1,0,3,2]
    else                          return __shfl_xor(v, MASK, 64);
}

// ---------------- Kernel 2: state evolution, TWO waves per circuit ---------
// Block = 128 threads = 2 waves = 1 circuit. Amplitude y = (w<<7)|(L<<1)|s,
// s in {0,1} packed in v2f. Qubit 0 (bit 7 = wave bit) -> one float4 LDS
// exchange per layer (double-buffered by parity, one barrier). Qubits 1..6 ->
// lane bits 5..0 (DPP / shfl_xor). Qubit 7 -> slot bit, local. CNOT chain ==
// Gray gather: new(w,L,s) = old(w, L^(L>>1)^(w<<5), s^(L&1)).
// Gates: lane-distributed vmem fetch (lane carries gate L&7), ping-pong
// prefetched one layer ahead in two NAMED float4s; readlane broadcast.
__global__ __launch_bounds__(128) void qemb_apply2w(
    const float4* __restrict__ g,  // [M, 256, 8]
    float* __restrict__ out)       // [M, 256] real parts
{
    __shared__ float4 xbuf[2][2][64];
    const int tid = threadIdx.x;
    const int w = __builtin_amdgcn_readfirstlane((int)(tid >> 6));
    const int L = tid & 63;
    const int m = blockIdx.x;

    v2f ar = {0.f, 0.f}, ai = {0.f, 0.f};
    if (tid == 0) ar.x = 1.f;   // |0...0>

    const float4* __restrict__ gm = g + ((size_t)m << 11);
    const int gq = L & 7;                // which gate this lane carries

    const float s0 = w ? -1.f : 1.f;
    float sgn[7];
#pragma unroll
    for (int q = 1; q < 7; ++q) sgn[q] = ((L >> (6 - q)) & 1) ? -1.f : 1.f;
    const int srcLane = (L ^ (L >> 1)) ^ (w << 5);
    const bool L0 = L & 1;

    // Cross-lane round for qubit Q (amp bit 7-Q = lane bit 6-Q), gates from lane Q.
#define ROUND(Q, MASK)                                                        \
    {                                                                         \
        const float g0 = bcast(Gd.x, Q), g1 = bcast(Gd.y, Q);                 \
        const float g2 = bcast(Gd.z, Q), g3 = bcast(Gd.w, Q);                 \
        const float s = sgn[Q];                                               \
        const float csr = g0, csi = s * g1, cpr = s * g2, cpi = g3;           \
        v2f pr, pi;                                                           \
        pr.x = lanexor<MASK>(ar.x); pr.y = lanexor<MASK>(ar.y);               \
        pi.x = lanexor<MASK>(ai.x); pi.y = lanexor<MASK>(ai.y);               \
        v2f nar = csr * ar - csi * ai + cpr * pr - cpi * pi;                  \
        v2f nai = csr * ai + csi * ar + cpr * pi + cpi * pr;                  \
        ar = nar; ai = nai;                                                   \
    }

    auto layer_step = [&](const float4 Gd, int parity) {
        // q = 0 (bit 7 = wave bit): LDS exchange with partner wave
        xbuf[parity][w][L] = make_float4(ar.x, ai.x, ar.y, ai.y);
        __syncthreads();
        const float4 pv = xbuf[parity][w ^ 1][L];
        {
            const float csr = bcast(Gd.x, 0);
            const float csi = s0 * bcast(Gd.y, 0);
            const float cpr = s0 * bcast(Gd.z, 0);
            const float cpi = bcast(Gd.w, 0);
            const v2f pr = {pv.x, pv.z}, pi = {pv.y, pv.w};
            const v2f nar = csr * ar - csi * ai + cpr * pr - cpi * pi;
            const v2f nai = csr * ai + csi * ar + cpr * pi + cpi * pr;
            ar = nar; ai = nai;
        }
        ROUND(1, 32) ROUND(2, 16) ROUND(3, 8) ROUND(4, 4) ROUND(5, 2) ROUND(6, 1)
        {   // q = 7: slot-local pair
            const float alr = bcast(Gd.x, 7), ali = bcast(Gd.y, 7);
            const float ber = bcast(Gd.z, 7), bei = bcast(Gd.w, 7);
            const float xr = ar.x, xi = ai.x, yr = ar.y, yi = ai.y;
            ar.x = alr * xr - ali * xi + ber * yr - bei * yi;
            ai.x = alr * xi + ali * xr + ber * yi + bei * yr;
            ar.y = -ber * xr - bei * xi + alr * yr + ali * yi;
            ai.y = -ber * xi + bei * xr + alr * yi - ali * yr;
        }
        // CNOT chain: Gray gather (source wave == own wave)
        const float t0r = __shfl(ar.x, srcLane, 64);
        const float t1r = __shfl(ar.y, srcLane, 64);
        const float t0i = __shfl(ai.x, srcLane, 64);
        const float t1i = __shfl(ai.y, srcLane, 64);
        ar.x = L0 ? t1r : t0r;  ar.y = L0 ? t0r : t1r;
        ai.x = L0 ? t1i : t0i;  ai.y = L0 ? t0i : t1i;
    };

    float4 GA = gm[0 * 8 + gq];   // layer 0 (lane-distributed)
    float4 GB;

    for (int i = 0; i < NLAYER; i += 2) {
        const int n1 = i + 1;
        GB = gm[n1 * 8 + gq];     // prefetch layer i+1 (in flight over step)
        layer_step(GA, 0);        // compute layer i
        const int n2 = (i + 2 < NLAYER) ? i + 2 : NLAYER - 1;
        GA = gm[n2 * 8 + gq];     // prefetch layer i+2
        layer_step(GB, 1);        // compute layer i+1
    }

    float2* o = reinterpret_cast<float2*>(out + ((size_t)m << 8) + (w << 7) + (L << 1));
    *o = make_float2(ar.x, ar.y);
#undef ROUND
}

// ---------------- Fallback: monolithic (known-good round-2 kernel) ---------
__global__ __launch_bounds__(256) void qemb_mono(
    const float* __restrict__ x, const float* __restrict__ p,
    float* __restrict__ out, int M)
{
    const int lane = threadIdx.x & 63;
    const int wave = threadIdx.x >> 6;
    const int m = blockIdx.x * 4 + wave;
    if (m >= M) return;
    float ar[4], ai[4];
#pragma unroll
    for (int j = 0; j < 4; ++j) { ar[j] = 0.f; ai[j] = 0.f; }
    if (lane == 0) ar[0] = 1.f;
    const float* __restrict__ xrow = x + (size_t)m * DIM;
    for (int i = 0; i < NLAYER; ++i) {
        const float he = 0.5f * xrow[i];
        const float* __restrict__ pl = p + i * (NQ * 3);
#pragma unroll
        for (int q = 0; q < NQ; ++q) {
            const float hx = he * pl[q * 3 + 0], hy = he * pl[q * 3 + 1], hz = he * pl[q * 3 + 2];
            const float cx = __cosf(hx), sx = __sinf(hx);
            const float cy = __cosf(hy), sy = __sinf(hy);
            const float cz = __cosf(hz), sz = __sinf(hz);
            const float A = cy * cx, B = sy * sx, C = sy * cx, D = cy * sx;
            const float alr = cz * A + sz * B, ali = cz * B - sz * A;
            const float ber = -(cz * C + sz * D), bei = sz * C - cz * D;
            if (q < 6) {
                const int sh = 5 - q;
                const float s = ((lane >> sh) & 1) ? -1.f : 1.f;
                const float csr = alr, csi = s * ali, cpr = s * ber, cpi = bei;
#pragma unroll
                for (int j = 0; j < 4; ++j) {
                    const float pr = __shfl_xor(ar[j], 1 << sh, 64);
                    const float pi = __shfl_xor(ai[j], 1 << sh, 64);
                    const float xr = ar[j], xi = ai[j];
                    ar[j] = csr * xr - csi * xi + cpr * pr - cpi * pi;
                    ai[j] = csr * xi + csi * xr + cpr * pi + cpi * pr;
                }
            } else {
                const int d = (q == 6) ? 2 : 1;
#pragma unroll
                for (int j0 = 0; j0 < 2; ++j0) {
                    const int a = (q == 6) ? j0 : j0 * 2, b = a + d;
                    const float xr = ar[a], xi = ai[a], yr = ar[b], yi = ai[b];
                    ar[a] = alr * xr - ali * xi + ber * yr - bei * yi;
                    ai[a] = alr * xi + ali * xr + ber * yi + bei * yr;
                    ar[b] = -ber * xr - bei * xi + alr * yr + ali * yi;
                    ai[b] = -ber * xi + bei * xr + alr * yi - ali * yr;
                }
            }
        }
        const int srcL = lane ^ (lane >> 1);
        float tr[4], ti[4];
#pragma unroll
        for (int s2 = 0; s2 < 4; ++s2) { tr[s2] = __shfl(ar[s2], srcL, 64); ti[s2] = __shfl(ai[s2], srcL, 64); }
        const int L0 = lane & 1;
        ar[0] = L0 ? tr[2] : tr[0];  ai[0] = L0 ? ti[2] : ti[0];
        ar[1] = L0 ? tr[3] : tr[1];  ai[1] = L0 ? ti[3] : ti[1];
        ar[2] = L0 ? tr[1] : tr[3];  ai[2] = L0 ? ti[1] : ti[3];
        ar[3] = L0 ? tr[0] : tr[2];  ai[3] = L0 ? ti[0] : ti[2];
    }
    float4* o = reinterpret_cast<float4*>(out + (size_t)m * DIM + lane * 4);
    *o = make_float4(ar[0], ar[1], ar[2], ar[3]);
}

extern "C" void kernel_launch(void* const* d_in, const int* in_sizes, int n_in,
                              void* d_out, int out_size, void* d_ws, size_t ws_size,
                              hipStream_t stream) {
    const float* x = (const float*)d_in[0];        // [8,256,256] fp32
    const float* qp = (const float*)d_in[1];       // [256,8,3] fp32
    float* out = (float*)d_out;                    // [8,256,256] fp32 real parts

    const int M = in_sizes[0] / DIM;               // 2048 circuits
    const size_t gates_bytes = (size_t)M * NLAYER * NQ * sizeof(float4);  // 67 MB

    if (ws_size >= gates_bytes) {
        float4* g = (float4*)d_ws;
        const int total = M * NLAYER * NQ;
        gates_gen<<<(total + 255) / 256, 256, 0, stream>>>(x, qp, g, total);
        qemb_apply2w<<<M, 128, 0, stream>>>(g, out);
    } else {
        qemb_mono<<<(M + 3) / 4, 256, 0, stream>>>(x, qp, out, M);
    }
}

// Round 10
// 325.487 us; speedup vs baseline: 1.2114x; 1.2114x over previous
//
#include <hip/hip_runtime.h>

#define NQ 8
#define DIM 256
#define NLAYER 256

typedef float v2f __attribute__((ext_vector_type(2)));
typedef float v4f __attribute__((ext_vector_type(4)));

// ---------------- Kernel 1: dense per-(m,layer,qubit) gate construction ----
// U = Rz @ Ry @ Rx = [[alpha, beta], [-conj(beta), conj(alpha)]]
// g[((m*256 + i)*8 + q)] = {alpha_r, alpha_i, beta_r, beta_i}
__global__ __launch_bounds__(256) void gates_gen(
    const float* __restrict__ x,   // [M, 256]
    const float* __restrict__ p,   // [256, 8, 3]
    float4* __restrict__ g,
    int total)
{
    const int idx = blockIdx.x * 256 + threadIdx.x;
    if (idx >= total) return;
    const int q = idx & 7;
    const int i = (idx >> 3) & 255;
    const int m = idx >> 11;

    const float he = 0.5f * x[(m << 8) | i];
    const float* __restrict__ pl = p + (i * 8 + q) * 3;
    const float hx = he * pl[0];
    const float hy = he * pl[1];
    const float hz = he * pl[2];
    const float cx = __cosf(hx), sx = __sinf(hx);
    const float cy = __cosf(hy), sy = __sinf(hy);
    const float cz = __cosf(hz), sz = __sinf(hz);
    const float A = cy * cx, B = sy * sx, C = sy * cx, D = cy * sx;
    const float alr = cz * A + sz * B;
    const float ali = cz * B - sz * A;
    const float ber = -(cz * C + sz * D);
    const float bei = sz * C - cz * D;
    g[idx] = make_float4(alr, ali, ber, bei);
}

// ---------------- packed-FP32 helpers (VOP3P) ------------------------------
// _l / _h : broadcast LOW/HIGH half of src0 to both result halves (op_sel).
// _n      : negate the product (neg_lo/neg_hi on src0).
__device__ __forceinline__ v2f pkmul(v2f a, v2f b) {
    v2f d; asm("v_pk_mul_f32 %0, %1, %2" : "=v"(d) : "v"(a), "v"(b)); return d;
}
__device__ __forceinline__ v2f pkmul_l(v2f a, v2f b) {
    v2f d; asm("v_pk_mul_f32 %0, %1, %2 op_sel:[0,0] op_sel_hi:[0,1]"
               : "=v"(d) : "v"(a), "v"(b)); return d;
}
__device__ __forceinline__ v2f pkmul_h(v2f a, v2f b) {
    v2f d; asm("v_pk_mul_f32 %0, %1, %2 op_sel:[1,0] op_sel_hi:[1,1]"
               : "=v"(d) : "v"(a), "v"(b)); return d;
}
__device__ __forceinline__ v2f pkfma(v2f a, v2f b, v2f c) {
    v2f d; asm("v_pk_fma_f32 %0, %1, %2, %3" : "=v"(d) : "v"(a), "v"(b), "v"(c)); return d;
}
__device__ __forceinline__ v2f pkfma_n(v2f a, v2f b, v2f c) {
    v2f d; asm("v_pk_fma_f32 %0, %1, %2, %3 neg_lo:[1,0,0] neg_hi:[1,0,0]"
               : "=v"(d) : "v"(a), "v"(b), "v"(c)); return d;
}
__device__ __forceinline__ v2f pkfma_l(v2f a, v2f b, v2f c) {
    v2f d; asm("v_pk_fma_f32 %0, %1, %2, %3 op_sel:[0,0,0] op_sel_hi:[0,1,1]"
               : "=v"(d) : "v"(a), "v"(b), "v"(c)); return d;
}
__device__ __forceinline__ v2f pkfma_ln(v2f a, v2f b, v2f c) {
    v2f d; asm("v_pk_fma_f32 %0, %1, %2, %3 op_sel:[0,0,0] op_sel_hi:[0,1,1] neg_lo:[1,0,0] neg_hi:[1,0,0]"
               : "=v"(d) : "v"(a), "v"(b), "v"(c)); return d;
}
__device__ __forceinline__ v2f pkfma_h(v2f a, v2f b, v2f c) {
    v2f d; asm("v_pk_fma_f32 %0, %1, %2, %3 op_sel:[1,0,0] op_sel_hi:[1,1,1]"
               : "=v"(d) : "v"(a), "v"(b), "v"(c)); return d;
}
__device__ __forceinline__ v2f pkfma_hn(v2f a, v2f b, v2f c) {
    v2f d; asm("v_pk_fma_f32 %0, %1, %2, %3 op_sel:[1,0,0] op_sel_hi:[1,1,1] neg_lo:[1,0,0] neg_hi:[1,0,0]"
               : "=v"(d) : "v"(a), "v"(b), "v"(c)); return d;
}

// Lane-xor via DPP (pure VALU, zero-wait).
template <int CTRL>
__device__ __forceinline__ float dppf(float v) {
    return __builtin_bit_cast(float,
        __builtin_amdgcn_update_dpp(0, __builtin_bit_cast(int, v),
                                    CTRL, 0xf, 0xf, true));
}
template <int MASK>
__device__ __forceinline__ float lanexor(float v) {
    if constexpr (MASK == 8)      return dppf<0x128>(v);  // row_ror:8
    else if constexpr (MASK == 2) return dppf<0x4E>(v);   // quad_perm [2,3,0,1]
    else if constexpr (MASK == 1) return dppf<0xB1>(v);   // quad_perm [1,0,3,2]
    else                          return __shfl_xor(v, MASK, 64);
}

// ---------------- Kernel 2: state evolution, one circuit per wave ----------
// Amplitude idx = lane*4 + j. Qubit q hits bit (7-q): q=0..5 -> lane bits
// (DPP/shfl_xor), q=6,7 -> slot bits. CNOT chain == Gray gather
// state'[y] = state[y ^ (y>>1)].
// Gate math in v_pk_*_f32 (2 floats/inst); gate coefficient pairs {alr,ali},
// {ber,bei} feed the VOP3P ops directly via op_sel half-broadcast -- zero
// readlanes, zero sign-muls (neg modifiers). Gates loaded as wave-uniform
// VMEM dwordx4 (opaque-zero VGPR index defeats s_load scalarization), named
// float4 ping-pong prefetched one layer ahead (R8-validated mechanism).

// Lane-qubit round: coefficients P={alr,ali}, Q={ber,bei}, S={s,s} per lane.
// nar = alr*ar - (s*ali)*ai + (s*ber)*pr - bei*pi
// nai = alr*ai + (s*ali)*ar + (s*ber)*pi + bei*pr
#define ROUND_L(P, Q, S, MASK) { \
    const v2f csi = pkmul_h(P, S); \
    const v2f cpr = pkmul_l(Q, S); \
    v2f pr01, pi01, pr23, pi23; \
    pr01.x = lanexor<MASK>(ar01.x); pr01.y = lanexor<MASK>(ar01.y); \
    pi01.x = lanexor<MASK>(ai01.x); pi01.y = lanexor<MASK>(ai01.y); \
    pr23.x = lanexor<MASK>(ar23.x); pr23.y = lanexor<MASK>(ar23.y); \
    pi23.x = lanexor<MASK>(ai23.x); pi23.y = lanexor<MASK>(ai23.y); \
    v2f t; \
    t = pkmul_l(P, ar01); t = pkfma_n(csi, ai01, t); t = pkfma(cpr, pr01, t); const v2f nar01 = pkfma_hn(Q, pi01, t); \
    t = pkmul_l(P, ai01); t = pkfma(csi, ar01, t);  t = pkfma(cpr, pi01, t); const v2f nai01 = pkfma_h(Q, pr01, t); \
    t = pkmul_l(P, ar23); t = pkfma_n(csi, ai23, t); t = pkfma(cpr, pr23, t); const v2f nar23 = pkfma_hn(Q, pi23, t); \
    t = pkmul_l(P, ai23); t = pkfma(csi, ar23, t);  t = pkfma(cpr, pi23, t); const v2f nai23 = pkfma_h(Q, pr23, t); \
    ar01 = nar01; ai01 = nai01; ar23 = nar23; ai23 = nai23; \
}

// q=6: couples group01 (bit=0) with group23 (bit=1), elementwise.
#define ROUND_Q6(P, Q) { \
    v2f t; \
    t = pkmul_l(P, ar01); t = pkfma_hn(P, ai01, t); t = pkfma_l(Q, ar23, t); const v2f nar01 = pkfma_hn(Q, ai23, t); \
    t = pkmul_l(P, ai01); t = pkfma_h(P, ar01, t);  t = pkfma_l(Q, ai23, t); const v2f nai01 = pkfma_h(Q, ar23, t); \
    t = pkmul_l(P, ar23); t = pkfma_h(P, ai23, t);  t = pkfma_ln(Q, ar01, t); const v2f nar23 = pkfma_hn(Q, ai01, t); \
    t = pkmul_l(P, ai23); t = pkfma_hn(P, ar23, t); t = pkfma_ln(Q, ai01, t); const v2f nai23 = pkfma_h(Q, ar01, t); \
    ar01 = nar01; ai01 = nai01; ar23 = nar23; ai23 = nai23; \
}

// q=7: couples the two slots inside each pair (scalar).
#define ROUND_Q7(G) { \
    const float alr = (G).x, ali = (G).y, ber = (G).z, bei = (G).w; \
    float xr = ar01.x, xi = ai01.x, yr = ar01.y, yi = ai01.y; \
    ar01.x = alr * xr - ali * xi + ber * yr - bei * yi; \
    ai01.x = alr * xi + ali * xr + ber * yi + bei * yr; \
    ar01.y = -ber * xr - bei * xi + alr * yr + ali * yi; \
    ai01.y = -ber * xi + bei * xr + alr * yi - ali * yr; \
    xr = ar23.x; xi = ai23.x; yr = ar23.y; yi = ai23.y; \
    ar23.x = alr * xr - ali * xi + ber * yr - bei * yi; \
    ai23.x = alr * xi + ali * xr + ber * yi + bei * yr; \
    ar23.y = -ber * xr - bei * xi + alr * yr + ali * yi; \
    ai23.y = -ber * xi + bei * xr + alr * yi - ali * yr; \
}

// CNOT chain: state'[y] = state[y ^ (y>>1)]
#define CNOTSTEP() { \
    const float t0r = __shfl(ar01.x, sl, 64), t1r = __shfl(ar01.y, sl, 64); \
    const float t2r = __shfl(ar23.x, sl, 64), t3r = __shfl(ar23.y, sl, 64); \
    const float t0i = __shfl(ai01.x, sl, 64), t1i = __shfl(ai01.y, sl, 64); \
    const float t2i = __shfl(ai23.x, sl, 64), t3i = __shfl(ai23.y, sl, 64); \
    ar01.x = L0 ? t2r : t0r;  ar01.y = L0 ? t3r : t1r; \
    ar23.x = L0 ? t1r : t3r;  ar23.y = L0 ? t0r : t2r; \
    ai01.x = L0 ? t2i : t0i;  ai01.y = L0 ? t3i : t1i; \
    ai23.x = L0 ? t1i : t3i;  ai23.y = L0 ? t0i : t2i; \
}

#define STEP(B) { \
    ROUND_L((B##0).lo, (B##0).hi, s2_0, 32) \
    ROUND_L((B##1).lo, (B##1).hi, s2_1, 16) \
    ROUND_L((B##2).lo, (B##2).hi, s2_2, 8) \
    ROUND_L((B##3).lo, (B##3).hi, s2_3, 4) \
    ROUND_L((B##4).lo, (B##4).hi, s2_4, 2) \
    ROUND_L((B##5).lo, (B##5).hi, s2_5, 1) \
    ROUND_Q6((B##6).lo, (B##6).hi) \
    ROUND_Q7(B##7) \
    CNOTSTEP() \
}

#define LOADL(B, L) { \
    const v4f* gp_ = gv4 + zero + (L) * 8; \
    B##0 = gp_[0]; B##1 = gp_[1]; B##2 = gp_[2]; B##3 = gp_[3]; \
    B##4 = gp_[4]; B##5 = gp_[5]; B##6 = gp_[6]; B##7 = gp_[7]; \
}

__global__ __launch_bounds__(256) void qemb_apply_pk(
    const v4f* __restrict__ g,     // [M, 256, 8]
    float* __restrict__ out,       // [M, 256] real parts
    int M)
{
    const int lane = threadIdx.x & 63;
    const int wave = __builtin_amdgcn_readfirstlane((int)(threadIdx.x >> 6));
    const int m = blockIdx.x * 4 + wave;
    if (m >= M) return;

    // Opaque zero in a VGPR: makes gate addresses formally divergent so the
    // compiler emits global_load_dwordx4 (vmcnt) instead of s_load (lgkmcnt,
    // which the DS shuffles would drain every round).
    int zero; asm("v_mov_b32 %0, 0" : "=v"(zero));

    v2f ar01 = {0.f, 0.f}, ai01 = {0.f, 0.f};
    v2f ar23 = {0.f, 0.f}, ai23 = {0.f, 0.f};
    if (lane == 0) ar01.x = 1.f;

    const v4f* __restrict__ gv4 = g + ((size_t)m << 11);

    const float g5 = ((lane >> 5) & 1) ? -1.f : 1.f;
    const float g4 = ((lane >> 4) & 1) ? -1.f : 1.f;
    const float g3 = ((lane >> 3) & 1) ? -1.f : 1.f;
    const float g2 = ((lane >> 2) & 1) ? -1.f : 1.f;
    const float g1 = ((lane >> 1) & 1) ? -1.f : 1.f;
    const float g0 = (lane & 1) ? -1.f : 1.f;
    const v2f s2_0 = {g5, g5}, s2_1 = {g4, g4}, s2_2 = {g3, g3};
    const v2f s2_3 = {g2, g2}, s2_4 = {g1, g1}, s2_5 = {g0, g0};

    const int sl = lane ^ (lane >> 1);   // CNOT source lane
    const bool L0 = lane & 1;

    v4f A0, A1, A2, A3, A4, A5, A6, A7;
    v4f B0, B1, B2, B3, B4, B5, B6, B7;

    LOADL(A, 0);
    for (int i = 0; i < NLAYER; i += 2) {
        LOADL(B, i + 1);                           // prefetch layer i+1
        STEP(A)                                    // compute layer i
        const int n2 = (i + 2 < NLAYER) ? i + 2 : NLAYER - 1;
        LOADL(A, n2);                              // prefetch layer i+2
        STEP(B)                                    // compute layer i+1
    }

    float4* o = reinterpret_cast<float4*>(out + (size_t)m * DIM + lane * 4);
    *o = make_float4(ar01.x, ar01.y, ar23.x, ar23.y);
}

// ---------------- Fallback: monolithic (known-good round-2 kernel) ---------
__global__ __launch_bounds__(256) void qemb_mono(
    const float* __restrict__ x, const float* __restrict__ p,
    float* __restrict__ out, int M)
{
    const int lane = threadIdx.x & 63;
    const int wave = threadIdx.x >> 6;
    const int m = blockIdx.x * 4 + wave;
    if (m >= M) return;
    float ar[4], ai[4];
#pragma unroll
    for (int j = 0; j < 4; ++j) { ar[j] = 0.f; ai[j] = 0.f; }
    if (lane == 0) ar[0] = 1.f;
    const float* __restrict__ xrow = x + (size_t)m * DIM;
    for (int i = 0; i < NLAYER; ++i) {
        const float he = 0.5f * xrow[i];
        const float* __restrict__ pl = p + i * (NQ * 3);
#pragma unroll
        for (int q = 0; q < NQ; ++q) {
            const float hx = he * pl[q * 3 + 0], hy = he * pl[q * 3 + 1], hz = he * pl[q * 3 + 2];
            const float cx = __cosf(hx), sx = __sinf(hx);
            const float cy = __cosf(hy), sy = __sinf(hy);
            const float cz = __cosf(hz), sz = __sinf(hz);
            const float A = cy * cx, B = sy * sx, C = sy * cx, D = cy * sx;
            const float alr = cz * A + sz * B, ali = cz * B - sz * A;
            const float ber = -(cz * C + sz * D), bei = sz * C - cz * D;
            if (q < 6) {
                const int sh = 5 - q;
                const float s = ((lane >> sh) & 1) ? -1.f : 1.f;
                const float csr = alr, csi = s * ali, cpr = s * ber, cpi = bei;
#pragma unroll
                for (int j = 0; j < 4; ++j) {
                    const float pr = __shfl_xor(ar[j], 1 << sh, 64);
                    const float pi = __shfl_xor(ai[j], 1 << sh, 64);
                    const float xr = ar[j], xi = ai[j];
                    ar[j] = csr * xr - csi * xi + cpr * pr - cpi * pi;
                    ai[j] = csr * xi + csi * xr + cpr * pi + cpi * pr;
                }
            } else {
                const int d = (q == 6) ? 2 : 1;
#pragma unroll
                for (int j0 = 0; j0 < 2; ++j0) {
                    const int a = (q == 6) ? j0 : j0 * 2, b = a + d;
                    const float xr = ar[a], xi = ai[a], yr = ar[b], yi = ai[b];
                    ar[a] = alr * xr - ali * xi + ber * yr - bei * yi;
                    ai[a] = alr * xi + ali * xr + ber * yi + bei * yr;
                    ar[b] = -ber * xr - bei * xi + alr * yr + ali * yi;
                    ai[b] = -ber * xi + bei * xr + alr * yi - ali * yr;
                }
            }
        }
        const int srcL = lane ^ (lane >> 1);
        float tr[4], ti[4];
#pragma unroll
        for (int s2 = 0; s2 < 4; ++s2) { tr[s2] = __shfl(ar[s2], srcL, 64); ti[s2] = __shfl(ai[s2], srcL, 64); }
        const int L0 = lane & 1;
        ar[0] = L0 ? tr[2] : tr[0];  ai[0] = L0 ? ti[2] : ti[0];
        ar[1] = L0 ? tr[3] : tr[1];  ai[1] = L0 ? ti[3] : ti[1];
        ar[2] = L0 ? tr[1] : tr[3];  ai[2] = L0 ? ti[1] : ti[3];
        ar[3] = L0 ? tr[0] : tr[2];  ai[3] = L0 ? ti[0] : ti[2];
    }
    float4* o = reinterpret_cast<float4*>(out + (size_t)m * DIM + lane * 4);
    *o = make_float4(ar[0], ar[1], ar[2], ar[3]);
}

extern "C" void kernel_launch(void* const* d_in, const int* in_sizes, int n_in,
                              void* d_out, int out_size, void* d_ws, size_t ws_size,
                              hipStream_t stream) {
    const float* x = (const float*)d_in[0];        // [8,256,256] fp32
    const float* qp = (const float*)d_in[1];       // [256,8,3] fp32
    float* out = (float*)d_out;                    // [8,256,256] fp32 real parts

    const int M = in_sizes[0] / DIM;               // 2048 circuits
    const size_t gates_bytes = (size_t)M * NLAYER * NQ * sizeof(float4);  // 67 MB

    if (ws_size >= gates_bytes) {
        float4* g = (float4*)d_ws;
        const int total = M * NLAYER * NQ;
        gates_gen<<<(total + 255) / 256, 256, 0, stream>>>(x, qp, g, total);
        qemb_apply_pk<<<(M + 3) / 4, 256, 0, stream>>>((const v4f*)g, out, M);
    } else {
        qemb_mono<<<(M + 3) / 4, 256, 0, stream>>>(x, qp, out, M);
    }
}